// Round 7
// baseline (805.457 us; speedup 1.0000x reference)
//
#include <hip/hip_runtime.h>

// VQ-VAE quantization: z [16384 x 512] f32, codebook [8192 x 512] f32.
// out = concat(z_st [16384*512] f32, vq_loss [1] f32).
//
// R4: MX-fp8 (e4m3, K=128 scaled MFMA) GEMM; packed (dist|idx) u32 argmin.
// R8: XCD remap + loss partials. R9 (deep-block) REGRESSED -> reverted.
// R10 (this):
//  - block = 1 mtile x 2 ktiles (128x256 out), 512 thr / 8 waves, 64x64
//    wave tiles (acc = 64 VGPR). A staged once per dt for both ktiles:
//    bytes/MFMA -25%; grid 4096; candV halves to 2 MB.
//  - spill kill (R5 wrote 57MB vs 4MB logical = scratch): cf-outer/rf-inner
//    fragment loop, 1 B frag + 1 A frag live -> peak ~100 VGPR <= 128 cap.
//  - reduce_loss fused into gather_out (atomic counter, last block reduces).
//  - NOTE: SQ_LDS_BANK_CONFLICT ~= 8cyc/global_load_lds (1KB wave-write /
//    128B LDS port) = staging-inherent, not a real conflict. Ignore.

#define M_ROWS 16384
#define K_CODES 8192
#define DIM 512
#define BM 128
#define KP 32                  // ktile-pairs (256 cols each)
#define NCOLS 256
#define OUT0_SIZE (M_ROWS * DIM)
#define GB_BLOCKS 1024

typedef int   i32x8 __attribute__((ext_vector_type(8)));
typedef float f32x4 __attribute__((ext_vector_type(4)));

template <bool HI>
__device__ __forceinline__ int pk8(float a, float b, int old) {
    return __builtin_amdgcn_cvt_pk_fp8_f32(a, b, old, HI);
}

__device__ __forceinline__ void gload_lds(const unsigned char* g, unsigned char* l) {
    __builtin_amdgcn_global_load_lds((const __attribute__((address_space(1))) void*)g,
                                     (__attribute__((address_space(3))) void*)l, 16, 0, 0);
}

// ---- kernel 1: fused converts ------------------------------------------
__global__ __launch_bounds__(256) void convert_all(
    const float* __restrict__ z, const float* __restrict__ cb,
    unsigned char* __restrict__ z8, unsigned char* __restrict__ cb8,
    float* __restrict__ enorm, unsigned int* __restrict__ counter)
{
    const int tid = threadIdx.x;
    if (blockIdx.x == 0 && tid == 0) *counter = 0;   // for gather_out's last-block
    if (blockIdx.x < K_CODES / 4) {
        const int w = tid >> 6, lane = tid & 63;
        const int row = blockIdx.x * 4 + w;
        const float* src = cb + (size_t)row * DIM + lane * 8;
        float4 a = *(const float4*)(src);
        float4 b = *(const float4*)(src + 4);
        float ns = a.x * a.x + a.y * a.y + a.z * a.z + a.w * a.w
                 + b.x * b.x + b.y * b.y + b.z * b.z + b.w * b.w;
        const float S = 8192.0f;                 // exact power of 2
        int lo = 0, hi = 0;
        lo = pk8<false>(a.x * S, a.y * S, lo); lo = pk8<true>(a.z * S, a.w * S, lo);
        hi = pk8<false>(b.x * S, b.y * S, hi); hi = pk8<true>(b.z * S, b.w * S, hi);
        *(int2*)(cb8 + (size_t)row * DIM + lane * 8) = make_int2(lo, hi);
        for (int m = 32; m; m >>= 1) ns += __shfl_down(ns, m, 64);
        if (lane == 0) enorm[row] = S * ns;      // 8192 * ||e||^2 (f32-exact norm)
    } else {
        size_t i = ((size_t)(blockIdx.x - K_CODES / 4) * 256 + tid) * 8;
        float4 a = *(const float4*)(z + i);
        float4 b = *(const float4*)(z + i + 4);
        int lo = 0, hi = 0;
        lo = pk8<false>(a.x, a.y, lo); lo = pk8<true>(a.z, a.w, lo);
        hi = pk8<false>(b.x, b.y, hi); hi = pk8<true>(b.z, b.w, hi);
        *(int2*)(z8 + i) = make_int2(lo, hi);
    }
}

// ---- kernel 2: MX-fp8 GEMM (128x256 per block) + packed-argmin ---------
__global__ __launch_bounds__(512, 4) void gemm_argmin(
    const unsigned char* __restrict__ z8, const unsigned char* __restrict__ cb8,
    const float* __restrict__ enorm, unsigned int* __restrict__ candV)
{
    __shared__ alignas(32) unsigned char As[BM * 128];      // 16 KB
    __shared__ alignas(32) unsigned char Bs[2][BM * 128];   // 32 KB
    __shared__ unsigned int cU[BM][4];                      //  2 KB

    const int tid = threadIdx.x;
    const int lane = tid & 63;
    const int w = tid >> 6;             // 0..7
    // XCD map: b&7 = XCD. Per XCD: 16 mtiles (1MB A, L2-hot), kpair walks
    // slowly (16 same-XCD blocks share each B-pair).
    const int b = blockIdx.x;
    const int xcd = b & 7;
    const int idx = b >> 3;             // 0..511
    const int kpair = idx >> 4;         // 0..31
    const int mtile = xcd * 16 + (idx & 15);
    const int mbase = mtile * BM;
    const int nb0 = kpair * NCOLS;      // base code id of the 256 cols

    const int rA = lane >> 3;           // row within 8-row chunk
    const int jG = ((lane & 7) ^ rA) * 16;  // pre-swizzled global 16B chunk
    const int quad = lane >> 4;
    const int l15 = lane & 15;
    const int sw = l15 & 7;
    const int wr = (w >> 2) * 64;       // wave row half: 0/64
    const int wcg = (w & 3) * 64;       // wave col quarter in [0,256)
    const int bsel = wcg >> 7;          // which B tile
    const int wcl = wcg & 64;           // col offset within that B tile
    // Chunks c0=(2q)^sw, c1=c0^1 = one aligned 32B block (R3-proven: the
    // per-lane half-swap is identical for A and B -> dot product exact).
    const int t32 = ((quad << 1) ^ (sw & 6)) * 16;

    float es[4];
#pragma unroll
    for (int cf = 0; cf < 4; ++cf) es[cf] = enorm[nb0 + wcg + cf * 16 + l15];

    f32x4 acc[16];
#pragma unroll
    for (int i = 0; i < 16; ++i) acc[i] = (f32x4){0.f, 0.f, 0.f, 0.f};

    for (int dt = 0; dt < 4; ++dt) {
        // stage A + B0 + B1 (6 gload_lds / thread)
#pragma unroll
        for (int i = 0; i < 2; ++i) {
            int c = w * 2 + i;          // chunk 0..15 (8 rows each)
            int row = c * 8 + rA;
            int col = dt * 128 + jG;
            gload_lds(z8 + (size_t)(mbase + row) * DIM + col,
                      As + c * 1024 + lane * 16);
            gload_lds(cb8 + (size_t)(nb0 + row) * DIM + col,
                      Bs[0] + c * 1024 + lane * 16);
            gload_lds(cb8 + (size_t)(nb0 + 128 + row) * DIM + col,
                      Bs[1] + c * 1024 + lane * 16);
        }
        __syncthreads();   // drains vmcnt(0): tiles ready
        // cf-outer / rf-inner: only 1 B frag + 1 A frag live -> no spill
#pragma unroll
        for (int cf = 0; cf < 4; ++cf) {
            i32x8 bf = *(const i32x8*)(Bs[bsel] + (wcl + cf * 16 + l15) * 128 + t32);
#pragma unroll
            for (int rf = 0; rf < 4; ++rf) {
                i32x8 a = *(const i32x8*)(As + (wr + rf * 16 + l15) * 128 + t32);
                acc[rf * 4 + cf] = __builtin_amdgcn_mfma_scale_f32_16x16x128_f8f6f4(
                    a, bf, acc[rf * 4 + cf],
                    0, 0,                      // cbsz=fp8(e4m3), blgp=fp8(e4m3)
                    0, 0x7F7F7F7F,             // opsel_a, scale_a = 1.0
                    0, 0x7F7F7F7F);            // opsel_b, scale_b = 1.0
            }
        }
        __syncthreads();   // all reads done before next stage overwrites
    }

    // epilogue: per-row argmin over this block's 256 cols.
    // C/D layout: col = lane&15, row = quad*4 + reg.
#pragma unroll
    for (int rf = 0; rf < 4; ++rf) {
#pragma unroll
        for (int r = 0; r < 4; ++r) {
            float bv = 3.4e38f; int bi = 0;
#pragma unroll
            for (int cf = 0; cf < 4; ++cf) {
                int col = nb0 + wcg + cf * 16 + l15;   // global code id (<8192)
                float dist = fmaf(-2.0f, acc[rf * 4 + cf][r], es[cf]);
                if (dist < bv) { bv = dist; bi = col; }  // strict <: low col on tie
            }
            unsigned u = __builtin_bit_cast(unsigned, bv);
            u ^= ((unsigned)(((int)u) >> 31)) | 0x80000000u;
            unsigned key = (u & 0xFFFFE000u) | (unsigned)bi;
#pragma unroll
            for (int sh = 1; sh < 16; sh <<= 1) {
                unsigned o = __shfl_xor(key, sh, 64);
                key = o < key ? o : key;
            }
            if (l15 == 0) cU[wr + rf * 16 + quad * 4 + r][w & 3] = key;
        }
    }
    __syncthreads();
    if (tid < BM) {
        unsigned k0 = cU[tid][0], k1 = cU[tid][1];
        unsigned k2 = cU[tid][2], k3 = cU[tid][3];
        unsigned ka = k0 < k1 ? k0 : k1;
        unsigned kb = k2 < k3 ? k2 : k3;
        candV[(size_t)kpair * M_ROWS + mbase + tid] = ka < kb ? ka : kb;
    }
}

// ---- kernel 3: candidate-reduce + gather + ST output + fused loss ------
// 4 waves/block, wave owns a row/iter: umin over 32 packed candidates,
// then 128 float4 slots. Last finishing block reduces the 1024 partials.
__global__ __launch_bounds__(256) void gather_out(
    const float* __restrict__ z, const float* __restrict__ cb,
    const unsigned int* __restrict__ candV, float* __restrict__ out,
    float* __restrict__ partials, unsigned int* __restrict__ counter)
{
    __shared__ float red[4];
    __shared__ unsigned int lastflag;
    const int tid = threadIdx.x;
    const int w = tid >> 6, lane = tid & 63;
    float lsum = 0.f;
#pragma unroll
    for (int it = 0; it < M_ROWS / (GB_BLOCKS * 4); ++it) {
        int row = (it * GB_BLOCKS + blockIdx.x) * 4 + w;
        unsigned key = candV[(size_t)(lane & 31) * M_ROWS + row];  // 2 lanes/entry: bcast
#pragma unroll
        for (int m = 1; m < 64; m <<= 1) {
            unsigned o = __shfl_xor(key, m, 64);
            key = o < key ? o : key;
        }
        int k = (int)(key & 8191u);
#pragma unroll
        for (int j = 0; j < 2; ++j) {
            int slot = lane + j * 64;
            float4 zv = ((const float4*)(z + (size_t)row * DIM))[slot];
            float4 cv = ((const float4*)(cb + (size_t)k * DIM))[slot];
            float dx = cv.x - zv.x, dy = cv.y - zv.y;
            float dz2 = cv.z - zv.z, dw = cv.w - zv.w;
            float4 o = {zv.x + dx, zv.y + dy, zv.z + dz2, zv.w + dw};  // z + sg(zq-z)
            ((float4*)(out + (size_t)row * DIM))[slot] = o;
            lsum += dx * dx + dy * dy + dz2 * dz2 + dw * dw;
        }
    }
    for (int m = 32; m; m >>= 1) lsum += __shfl_down(lsum, m, 64);
    if (lane == 0) red[w] = lsum;
    __syncthreads();
    if (tid == 0) {
        float t = (red[0] + red[1]) + (red[2] + red[3]);
        __hip_atomic_store(&partials[blockIdx.x], t,
                           __ATOMIC_RELAXED, __HIP_MEMORY_SCOPE_AGENT);
        unsigned prev = __hip_atomic_fetch_add(counter, 1u,
                           __ATOMIC_ACQ_REL, __HIP_MEMORY_SCOPE_AGENT);
        lastflag = (prev == GB_BLOCKS - 1) ? 1u : 0u;
    }
    __syncthreads();
    if (lastflag) {
        float s = 0.f;
#pragma unroll
        for (int i = 0; i < GB_BLOCKS / 256; ++i)
            s += __hip_atomic_load(&partials[i * 256 + tid],
                                   __ATOMIC_RELAXED, __HIP_MEMORY_SCOPE_AGENT);
        for (int m = 32; m; m >>= 1) s += __shfl_down(s, m, 64);
        if ((tid & 63) == 0) red[tid >> 6] = s;
        __syncthreads();
        if (tid == 0)
            out[OUT0_SIZE] = ((red[0] + red[1]) + (red[2] + red[3]))
                             * (1.1f / (float)OUT0_SIZE);
    }
}

extern "C" void kernel_launch(void* const* d_in, const int* in_sizes, int n_in,
                              void* d_out, int out_size, void* d_ws, size_t ws_size,
                              hipStream_t stream) {
    const float* z = (const float*)d_in[0];     // 16*1024*512
    const float* cb = (const float*)d_in[1];    // 8192*512
    float* out = (float*)d_out;                 // 8388608 + 1
    char* ws = (char*)d_ws;

    // ws layout (bytes)
    unsigned char* z8      = (unsigned char*)(ws);            //  8,388,608
    unsigned char* cb8     = (unsigned char*)(ws + 8388608);  //  4,194,304
    float* enorm           = (float*)(ws + 12582912);         //     32,768
    unsigned int* candV    = (unsigned int*)(ws + 12615680);  //  2,097,152
    float* partials        = (float*)(ws + 14712832);         //      4,096
    unsigned int* counter  = (unsigned int*)(ws + 14716928);  //          4

    convert_all<<<K_CODES / 4 + M_ROWS * DIM / 2048, 256, 0, stream>>>(
        z, cb, z8, cb8, enorm, counter);
    gemm_argmin<<<KP * (M_ROWS / BM), 512, 0, stream>>>(z8, cb8, enorm, candV);
    gather_out<<<GB_BLOCKS, 256, 0, stream>>>(z, cb, candV, out, partials, counter);
}

// Round 8
// 338.933 us; speedup vs baseline: 2.3764x; 2.3764x over previous
//
#include <hip/hip_runtime.h>

// VQ-VAE quantization: z [16384 x 512] f32, codebook [8192 x 512] f32.
// out = concat(z_st [16384*512] f32, vq_loss [1] f32).
//
// R4: MX-fp8 (e4m3, K=128 scaled MFMA) GEMM; packed (dist|idx) u32 argmin.
// R8: XCD remap + loss partials. R10: 128x256 block (A staged once per 2
// B-tiles), fused last-block loss reduce.
// R11 (this): fix R10's catastrophic spill — __launch_bounds__ 2nd arg is
// min BLOCKS/CU on this hipcc: (512,4) capped VGPR at 64 (= acc alone),
// spilling 1.3GB/dispatch. Now (512,2) -> cap 128. Fragment order back to
// R5-proven B-quad hoist + A-per-rf (liveness ~115; also 4x fewer LDS
// A-reads than cf-outer).

#define M_ROWS 16384
#define K_CODES 8192
#define DIM 512
#define BM 128
#define KP 32                  // ktile-pairs (256 cols each)
#define NCOLS 256
#define OUT0_SIZE (M_ROWS * DIM)
#define GB_BLOCKS 1024

typedef int   i32x8 __attribute__((ext_vector_type(8)));
typedef float f32x4 __attribute__((ext_vector_type(4)));

template <bool HI>
__device__ __forceinline__ int pk8(float a, float b, int old) {
    return __builtin_amdgcn_cvt_pk_fp8_f32(a, b, old, HI);
}

__device__ __forceinline__ void gload_lds(const unsigned char* g, unsigned char* l) {
    __builtin_amdgcn_global_load_lds((const __attribute__((address_space(1))) void*)g,
                                     (__attribute__((address_space(3))) void*)l, 16, 0, 0);
}

// ---- kernel 1: fused converts ------------------------------------------
__global__ __launch_bounds__(256) void convert_all(
    const float* __restrict__ z, const float* __restrict__ cb,
    unsigned char* __restrict__ z8, unsigned char* __restrict__ cb8,
    float* __restrict__ enorm, unsigned int* __restrict__ counter)
{
    const int tid = threadIdx.x;
    if (blockIdx.x == 0 && tid == 0) *counter = 0;   // for gather_out's last-block
    if (blockIdx.x < K_CODES / 4) {
        const int w = tid >> 6, lane = tid & 63;
        const int row = blockIdx.x * 4 + w;
        const float* src = cb + (size_t)row * DIM + lane * 8;
        float4 a = *(const float4*)(src);
        float4 b = *(const float4*)(src + 4);
        float ns = a.x * a.x + a.y * a.y + a.z * a.z + a.w * a.w
                 + b.x * b.x + b.y * b.y + b.z * b.z + b.w * b.w;
        const float S = 8192.0f;                 // exact power of 2
        int lo = 0, hi = 0;
        lo = pk8<false>(a.x * S, a.y * S, lo); lo = pk8<true>(a.z * S, a.w * S, lo);
        hi = pk8<false>(b.x * S, b.y * S, hi); hi = pk8<true>(b.z * S, b.w * S, hi);
        *(int2*)(cb8 + (size_t)row * DIM + lane * 8) = make_int2(lo, hi);
        for (int m = 32; m; m >>= 1) ns += __shfl_down(ns, m, 64);
        if (lane == 0) enorm[row] = S * ns;      // 8192 * ||e||^2 (f32-exact norm)
    } else {
        size_t i = ((size_t)(blockIdx.x - K_CODES / 4) * 256 + tid) * 8;
        float4 a = *(const float4*)(z + i);
        float4 b = *(const float4*)(z + i + 4);
        int lo = 0, hi = 0;
        lo = pk8<false>(a.x, a.y, lo); lo = pk8<true>(a.z, a.w, lo);
        hi = pk8<false>(b.x, b.y, hi); hi = pk8<true>(b.z, b.w, hi);
        *(int2*)(z8 + i) = make_int2(lo, hi);
    }
}

// ---- kernel 2: MX-fp8 GEMM (128x256 per block) + packed-argmin ---------
__global__ __launch_bounds__(512, 2) void gemm_argmin(
    const unsigned char* __restrict__ z8, const unsigned char* __restrict__ cb8,
    const float* __restrict__ enorm, unsigned int* __restrict__ candV)
{
    __shared__ alignas(32) unsigned char As[BM * 128];      // 16 KB
    __shared__ alignas(32) unsigned char Bs[2][BM * 128];   // 32 KB
    __shared__ unsigned int cU[BM][4];                      //  2 KB

    const int tid = threadIdx.x;
    const int lane = tid & 63;
    const int w = tid >> 6;             // 0..7
    // XCD map: b&7 = XCD. Per XCD: 16 mtiles (1MB A, L2-hot), kpair walks
    // slowly (16 same-XCD blocks share each B-pair).
    const int b = blockIdx.x;
    const int xcd = b & 7;
    const int idx = b >> 3;             // 0..511
    const int kpair = idx >> 4;         // 0..31
    const int mtile = xcd * 16 + (idx & 15);
    const int mbase = mtile * BM;
    const int nb0 = kpair * NCOLS;      // base code id of the 256 cols

    const int rA = lane >> 3;           // row within 8-row chunk
    const int jG = ((lane & 7) ^ rA) * 16;  // pre-swizzled global 16B chunk
    const int quad = lane >> 4;
    const int l15 = lane & 15;
    const int sw = l15 & 7;
    const int wr = (w >> 2) * 64;       // wave row half: 0/64
    const int wcg = (w & 3) * 64;       // wave col quarter in [0,256)
    const int bsel = wcg >> 7;          // which B tile
    const int wcl = wcg & 64;           // col offset within that B tile
    // Chunks c0=(2q)^sw, c1=c0^1 = one aligned 32B block (R3-proven: the
    // per-lane half-swap is identical for A and B -> dot product exact).
    const int t32 = ((quad << 1) ^ (sw & 6)) * 16;

    float es[4];
#pragma unroll
    for (int cf = 0; cf < 4; ++cf) es[cf] = enorm[nb0 + wcg + cf * 16 + l15];

    f32x4 acc[16];
#pragma unroll
    for (int i = 0; i < 16; ++i) acc[i] = (f32x4){0.f, 0.f, 0.f, 0.f};

    for (int dt = 0; dt < 4; ++dt) {
        // stage A + B0 + B1 (6 gload_lds / thread)
#pragma unroll
        for (int i = 0; i < 2; ++i) {
            int c = w * 2 + i;          // chunk 0..15 (8 rows each)
            int row = c * 8 + rA;
            int col = dt * 128 + jG;
            gload_lds(z8 + (size_t)(mbase + row) * DIM + col,
                      As + c * 1024 + lane * 16);
            gload_lds(cb8 + (size_t)(nb0 + row) * DIM + col,
                      Bs[0] + c * 1024 + lane * 16);
            gload_lds(cb8 + (size_t)(nb0 + 128 + row) * DIM + col,
                      Bs[1] + c * 1024 + lane * 16);
        }
        __syncthreads();   // drains vmcnt(0): tiles ready
        // R5-proven order: hoist 4 B frags, load A once per rf.
        i32x8 bfr[4];
#pragma unroll
        for (int cf = 0; cf < 4; ++cf)
            bfr[cf] = *(const i32x8*)(Bs[bsel] + (wcl + cf * 16 + l15) * 128 + t32);
#pragma unroll
        for (int rf = 0; rf < 4; ++rf) {
            i32x8 a = *(const i32x8*)(As + (wr + rf * 16 + l15) * 128 + t32);
#pragma unroll
            for (int cf = 0; cf < 4; ++cf)
                acc[rf * 4 + cf] = __builtin_amdgcn_mfma_scale_f32_16x16x128_f8f6f4(
                    a, bfr[cf], acc[rf * 4 + cf],
                    0, 0,                      // cbsz=fp8(e4m3), blgp=fp8(e4m3)
                    0, 0x7F7F7F7F,             // opsel_a, scale_a = 1.0
                    0, 0x7F7F7F7F);            // opsel_b, scale_b = 1.0
        }
        __syncthreads();   // all reads done before next stage overwrites
    }

    // epilogue: per-row argmin over this block's 256 cols.
    // C/D layout: col = lane&15, row = quad*4 + reg.
#pragma unroll
    for (int rf = 0; rf < 4; ++rf) {
#pragma unroll
        for (int r = 0; r < 4; ++r) {
            float bv = 3.4e38f; int bi = 0;
#pragma unroll
            for (int cf = 0; cf < 4; ++cf) {
                int col = nb0 + wcg + cf * 16 + l15;   // global code id (<8192)
                float dist = fmaf(-2.0f, acc[rf * 4 + cf][r], es[cf]);
                if (dist < bv) { bv = dist; bi = col; }  // strict <: low col on tie
            }
            unsigned u = __builtin_bit_cast(unsigned, bv);
            u ^= ((unsigned)(((int)u) >> 31)) | 0x80000000u;
            unsigned key = (u & 0xFFFFE000u) | (unsigned)bi;
#pragma unroll
            for (int sh = 1; sh < 16; sh <<= 1) {
                unsigned o = __shfl_xor(key, sh, 64);
                key = o < key ? o : key;
            }
            if (l15 == 0) cU[wr + rf * 16 + quad * 4 + r][w & 3] = key;
        }
    }
    __syncthreads();
    if (tid < BM) {
        unsigned k0 = cU[tid][0], k1 = cU[tid][1];
        unsigned k2 = cU[tid][2], k3 = cU[tid][3];
        unsigned ka = k0 < k1 ? k0 : k1;
        unsigned kb = k2 < k3 ? k2 : k3;
        candV[(size_t)kpair * M_ROWS + mbase + tid] = ka < kb ? ka : kb;
    }
}

// ---- kernel 3: candidate-reduce + gather + ST output + fused loss ------
// 4 waves/block, wave owns a row/iter: umin over 32 packed candidates,
// then 128 float4 slots. Last finishing block reduces the 1024 partials.
__global__ __launch_bounds__(256) void gather_out(
    const float* __restrict__ z, const float* __restrict__ cb,
    const unsigned int* __restrict__ candV, float* __restrict__ out,
    float* __restrict__ partials, unsigned int* __restrict__ counter)
{
    __shared__ float red[4];
    __shared__ unsigned int lastflag;
    const int tid = threadIdx.x;
    const int w = tid >> 6, lane = tid & 63;
    float lsum = 0.f;
#pragma unroll
    for (int it = 0; it < M_ROWS / (GB_BLOCKS * 4); ++it) {
        int row = (it * GB_BLOCKS + blockIdx.x) * 4 + w;
        unsigned key = candV[(size_t)(lane & 31) * M_ROWS + row];  // 2 lanes/entry: bcast
#pragma unroll
        for (int m = 1; m < 64; m <<= 1) {
            unsigned o = __shfl_xor(key, m, 64);
            key = o < key ? o : key;
        }
        int k = (int)(key & 8191u);
#pragma unroll
        for (int j = 0; j < 2; ++j) {
            int slot = lane + j * 64;
            float4 zv = ((const float4*)(z + (size_t)row * DIM))[slot];
            float4 cv = ((const float4*)(cb + (size_t)k * DIM))[slot];
            float dx = cv.x - zv.x, dy = cv.y - zv.y;
            float dz2 = cv.z - zv.z, dw = cv.w - zv.w;
            float4 o = {zv.x + dx, zv.y + dy, zv.z + dz2, zv.w + dw};  // z + sg(zq-z)
            ((float4*)(out + (size_t)row * DIM))[slot] = o;
            lsum += dx * dx + dy * dy + dz2 * dz2 + dw * dw;
        }
    }
    for (int m = 32; m; m >>= 1) lsum += __shfl_down(lsum, m, 64);
    if (lane == 0) red[w] = lsum;
    __syncthreads();
    if (tid == 0) {
        float t = (red[0] + red[1]) + (red[2] + red[3]);
        __hip_atomic_store(&partials[blockIdx.x], t,
                           __ATOMIC_RELAXED, __HIP_MEMORY_SCOPE_AGENT);
        unsigned prev = __hip_atomic_fetch_add(counter, 1u,
                           __ATOMIC_ACQ_REL, __HIP_MEMORY_SCOPE_AGENT);
        lastflag = (prev == GB_BLOCKS - 1) ? 1u : 0u;
    }
    __syncthreads();
    if (lastflag) {
        float s = 0.f;
#pragma unroll
        for (int i = 0; i < GB_BLOCKS / 256; ++i)
            s += __hip_atomic_load(&partials[i * 256 + tid],
                                   __ATOMIC_RELAXED, __HIP_MEMORY_SCOPE_AGENT);
        for (int m = 32; m; m >>= 1) s += __shfl_down(s, m, 64);
        if ((tid & 63) == 0) red[tid >> 6] = s;
        __syncthreads();
        if (tid == 0)
            out[OUT0_SIZE] = ((red[0] + red[1]) + (red[2] + red[3]))
                             * (1.1f / (float)OUT0_SIZE);
    }
}

extern "C" void kernel_launch(void* const* d_in, const int* in_sizes, int n_in,
                              void* d_out, int out_size, void* d_ws, size_t ws_size,
                              hipStream_t stream) {
    const float* z = (const float*)d_in[0];     // 16*1024*512
    const float* cb = (const float*)d_in[1];    // 8192*512
    float* out = (float*)d_out;                 // 8388608 + 1
    char* ws = (char*)d_ws;

    // ws layout (bytes)
    unsigned char* z8      = (unsigned char*)(ws);            //  8,388,608
    unsigned char* cb8     = (unsigned char*)(ws + 8388608);  //  4,194,304
    float* enorm           = (float*)(ws + 12582912);         //     32,768
    unsigned int* candV    = (unsigned int*)(ws + 12615680);  //  2,097,152
    float* partials        = (float*)(ws + 14712832);         //      4,096
    unsigned int* counter  = (unsigned int*)(ws + 14716928);  //          4

    convert_all<<<K_CODES / 4 + M_ROWS * DIM / 2048, 256, 0, stream>>>(
        z, cb, z8, cb8, enorm, counter);
    gemm_argmin<<<KP * (M_ROWS / BM), 512, 0, stream>>>(z8, cb8, enorm, candV);
    gather_out<<<GB_BLOCKS, 256, 0, stream>>>(z, cb, candV, out, partials, counter);
}